// Round 2
// baseline (4906.715 us; speedup 1.0000x reference)
//
#include <hip/hip_runtime.h>
#include <math.h>

// Problem dims (fixed by reference)
#define S_DIM 512
#define B_DIM 64
#define IN_DIM 512
#define H_DIM 1024
#define OUT_DIM 512
#define BH (B_DIM * H_DIM)      // 65536

// ---------------- fp32 tiled GEMM with bias: C = A @ W + bias ----------------
// A: [M,K] row-major, W: [K,N] row-major, bias: [N], C: [M,N]
// blockIdx.z in [0,3) selects (W,bias,C) triple -> fuses the 3 gate GEMMs.
#define BM 128
#define BN 128
#define BK 8
#define TM 8
#define TN 8

__global__ __launch_bounds__(256) void gemm3_bias(
    const float* __restrict__ A,
    const float* __restrict__ W0, const float* __restrict__ W1, const float* __restrict__ W2,
    const float* __restrict__ b0, const float* __restrict__ b1, const float* __restrict__ b2,
    float* __restrict__ C0, float* __restrict__ C1, float* __restrict__ C2,
    int M, int N, int K)
{
    const int z = blockIdx.z;
    const float* __restrict__ W    = (z == 0) ? W0 : (z == 1) ? W1 : W2;
    const float* __restrict__ bias = (z == 0) ? b0 : (z == 1) ? b1 : b2;
    float* __restrict__ C          = (z == 0) ? C0 : (z == 1) ? C1 : C2;

    __shared__ float As[BK][BM];      // transposed A tile
    __shared__ float Bs[BK][BN + 4];  // +4 keeps 16B alignment, breaks pow2 stride

    const int tid = threadIdx.x;
    const int row0 = blockIdx.y * BM;
    const int col0 = blockIdx.x * BN;

    const int arow = tid >> 1;           // 0..127
    const int acol = (tid & 1) << 2;     // 0 or 4
    const int brow = tid >> 5;           // 0..7
    const int bcol = (tid & 31) << 2;    // 0..124

    const int ty = tid >> 4;   // 0..15
    const int tx = tid & 15;   // 0..15

    float acc[TM][TN];
#pragma unroll
    for (int i = 0; i < TM; ++i)
#pragma unroll
        for (int j = 0; j < TN; ++j) acc[i][j] = 0.f;

    for (int k0 = 0; k0 < K; k0 += BK) {
        float4 av = *(const float4*)(A + (size_t)(row0 + arow) * K + k0 + acol);
        float4 bv = *(const float4*)(W + (size_t)(k0 + brow) * N + col0 + bcol);
        As[acol + 0][arow] = av.x;
        As[acol + 1][arow] = av.y;
        As[acol + 2][arow] = av.z;
        As[acol + 3][arow] = av.w;
        *(float4*)&Bs[brow][bcol] = bv;
        __syncthreads();

#pragma unroll
        for (int kk = 0; kk < BK; ++kk) {
            float a[TM], b[TN];
            *(float4*)&a[0] = *(const float4*)&As[kk][ty * TM];
            *(float4*)&a[4] = *(const float4*)&As[kk][ty * TM + 4];
            *(float4*)&b[0] = *(const float4*)&Bs[kk][tx * TN];
            *(float4*)&b[4] = *(const float4*)&Bs[kk][tx * TN + 4];
#pragma unroll
            for (int i = 0; i < TM; ++i)
#pragma unroll
                for (int j = 0; j < TN; ++j)
                    acc[i][j] += a[i] * b[j];
        }
        __syncthreads();
    }

    float bvals[TN];
#pragma unroll
    for (int j = 0; j < TN; ++j) bvals[j] = bias[col0 + tx * TN + j];

#pragma unroll
    for (int i = 0; i < TM; ++i) {
        const size_t r = (size_t)(row0 + ty * TM + i);
        float* crow = C + r * N + col0 + tx * TN;
        float4 v0, v1;
        v0.x = acc[i][0] + bvals[0]; v0.y = acc[i][1] + bvals[1];
        v0.z = acc[i][2] + bvals[2]; v0.w = acc[i][3] + bvals[3];
        v1.x = acc[i][4] + bvals[4]; v1.y = acc[i][5] + bvals[5];
        v1.z = acc[i][6] + bvals[6]; v1.w = acc[i][7] + bvals[7];
        *(float4*)crow = v0;
        *(float4*)(crow + 4) = v1;
    }
}

// ---------------- BRC scan over one time-chunk ----------------
// xa/xc/xh/y: [T_c, B*H] chunk buffers. h_in: initial state (h0 for chunk 0,
// else h_state). h_out: running state (the d_out h_last slot — doubles as the
// final output). One thread per (b,j); no inter-thread deps.
__global__ __launch_bounds__(256) void brc_scan_chunk(
    const float* __restrict__ xa, const float* __restrict__ xc,
    const float* __restrict__ xh, const float* __restrict__ wa,
    const float* __restrict__ wc, const float* __restrict__ h_in,
    float* __restrict__ y, float* __restrict__ h_out, int T_c)
{
    const int idx = blockIdx.x * blockDim.x + threadIdx.x;  // 0..BH-1
    const int j = idx & (H_DIM - 1);
    float h = h_in[idx];
    const float wa_j = wa[j];
    const float wc_j = wc[j];

    for (int t = 0; t < T_c; ++t) {
        const size_t base = (size_t)t * BH + idx;
        const float xat = xa[base];
        const float xct = xc[base];
        const float xht = xh[base];
        const float a = 1.f + tanhf(xat + wa_j * h);
        const float zc = xct + wc_j * h;
        const float c = 1.f / (1.f + expf(-zc));
        h = c * h + (1.f - c) * tanhf(xht + a * h);
        y[base] = h;
    }
    h_out[idx] = h;
}

extern "C" void kernel_launch(void* const* d_in, const int* in_sizes, int n_in,
                              void* d_out, int out_size, void* d_ws, size_t ws_size,
                              hipStream_t stream) {
    const float* x    = (const float*)d_in[0];   // [S,B,IN]
    const float* h0   = (const float*)d_in[1];   // [L,B,H]
    const float* Ua0  = (const float*)d_in[2];
    const float* Uc0  = (const float*)d_in[3];
    const float* Uh0  = (const float*)d_in[4];
    const float* wa0  = (const float*)d_in[5];
    const float* wc0  = (const float*)d_in[6];
    const float* ba0  = (const float*)d_in[7];
    const float* bc0  = (const float*)d_in[8];
    const float* bh0  = (const float*)d_in[9];
    const float* Ua1  = (const float*)d_in[10];
    const float* Uc1  = (const float*)d_in[11];
    const float* Uh1  = (const float*)d_in[12];
    const float* wa1  = (const float*)d_in[13];
    const float* wc1  = (const float*)d_in[14];
    const float* ba1  = (const float*)d_in[15];
    const float* bc1  = (const float*)d_in[16];
    const float* bh1  = (const float*)d_in[17];
    const float* Wdec = (const float*)d_in[18];
    const float* bdec = (const float*)d_in[19];

    float* outF = (float*)d_out;
    float* out_seq  = outF;                                   // [S,B,OUT]
    float* h_last0  = outF + (size_t)S_DIM * B_DIM * OUT_DIM; // [B,H]
    float* h_last1  = h_last0 + BH;                           // [B,H]

    // Pick the largest power-of-two time-chunk T_c whose scratch
    // (5 buffers of T_c*B*H floats: xa,xc,xh,y0,y1) fits in ws_size.
    int T_c = 512;
    while (T_c > 1 && (size_t)5 * T_c * BH * sizeof(float) > ws_size) T_c >>= 1;
    const size_t chunk_elems = (size_t)T_c * BH;

    float* xa = (float*)d_ws;
    float* xc = xa + chunk_elems;
    float* xh = xc + chunk_elems;
    float* y0 = xh + chunk_elems;
    float* y1 = y0 + chunk_elems;

    const int n_chunks = S_DIM / T_c;
    const int Mc = T_c * B_DIM;

    dim3 blk(256);
    dim3 grid_g1(H_DIM / BN, Mc / BM, 3);   // 3 gate GEMMs fused via z
    dim3 grid_dec(OUT_DIM / BN, Mc / BM, 1);
    dim3 grid_scan(BH / 256);

    for (int ci = 0; ci < n_chunks; ++ci) {
        const float* x_chunk = x + (size_t)ci * Mc * IN_DIM;
        float* out_chunk = out_seq + (size_t)ci * Mc * OUT_DIM;

        // layer 0 gate projections for this chunk
        gemm3_bias<<<grid_g1, blk, 0, stream>>>(
            x_chunk, Ua0, Uc0, Uh0, ba0, bc0, bh0, xa, xc, xh,
            Mc, H_DIM, IN_DIM);
        // layer 0 scan (h carried in h_last0 slot of d_out)
        brc_scan_chunk<<<grid_scan, blk, 0, stream>>>(
            xa, xc, xh, wa0, wc0, (ci == 0) ? h0 : h_last0, y0, h_last0, T_c);

        // layer 1 gate projections
        gemm3_bias<<<grid_g1, blk, 0, stream>>>(
            y0, Ua1, Uc1, Uh1, ba1, bc1, bh1, xa, xc, xh,
            Mc, H_DIM, H_DIM);
        // layer 1 scan
        brc_scan_chunk<<<grid_scan, blk, 0, stream>>>(
            xa, xc, xh, wa1, wc1, (ci == 0) ? (h0 + BH) : h_last1, y1, h_last1, T_c);

        // decoder for this chunk
        gemm3_bias<<<grid_dec, blk, 0, stream>>>(
            y1, Wdec, Wdec, Wdec, bdec, bdec, bdec, out_chunk, out_chunk, out_chunk,
            Mc, OUT_DIM, H_DIM);
    }
}

// Round 5
// 2141.208 us; speedup vs baseline: 2.2916x; 2.2916x over previous
//
#include <hip/hip_runtime.h>
#include <math.h>

// Problem dims (fixed by reference)
#define S_DIM 512
#define B_DIM 64
#define IN_DIM 512
#define H_DIM 1024
#define OUT_DIM 512
#define BH (B_DIM * H_DIM)      // 65536

typedef unsigned short ushort_t;
typedef unsigned int uint_t;
using f32x4 = __attribute__((ext_vector_type(4))) float;
using f16x8 = __attribute__((ext_vector_type(8))) _Float16;  // 8 f16 (4 VGPRs)

#define LO_SCALE 2048.0f          // 2^11
#define LO_INV   (1.0f / 2048.0f)

// ---- fp32 -> f16 hi/lo split: x ~= hi + lo/2048 (lo holds residual * 2^11) ----
__device__ __forceinline__ void split_f16(float v, ushort_t& hi, ushort_t& lo) {
    _Float16 h = (_Float16)v;
    float r = (v - (float)h) * LO_SCALE;
    _Float16 l = (_Float16)r;
    hi = __builtin_bit_cast(ushort_t, h);
    lo = __builtin_bit_cast(ushort_t, l);
}
__device__ __forceinline__ ushort_t f2h(float f) {
    _Float16 h = (_Float16)f;
    return __builtin_bit_cast(ushort_t, h);
}

__device__ __forceinline__ void gload_lds16(const ushort_t* g, ushort_t* l) {
    __builtin_amdgcn_global_load_lds(
        (const __attribute__((address_space(1))) void*)g,
        (__attribute__((address_space(3))) void*)l, 16, 0, 0);
}

// ---------------- weight transpose + split: W[K,N] f32 -> Whi/Wlo [N,K] f16 ----------------
__global__ __launch_bounds__(256) void transpose_split_f16(
    const float* __restrict__ W, ushort_t* __restrict__ Whi, ushort_t* __restrict__ Wlo,
    int K, int N)
{
    __shared__ float tile[32][33];
    const int k0 = blockIdx.y * 32, n0 = blockIdx.x * 32;
    const int tx = threadIdx.x & 31, ty = threadIdx.x >> 5;   // ty 0..7
#pragma unroll
    for (int r = 0; r < 32; r += 8)
        tile[ty + r][tx] = W[(size_t)(k0 + ty + r) * N + n0 + tx];
    __syncthreads();
#pragma unroll
    for (int r = 0; r < 32; r += 8) {
        ushort_t hi, lo;
        split_f16(tile[tx][ty + r], hi, lo);
        const size_t o = (size_t)(n0 + ty + r) * K + k0 + tx;
        Whi[o] = hi;
        Wlo[o] = lo;
    }
}

// ---------------- f32 -> f16 hi/lo split (activations, contiguous) ----------------
__global__ __launch_bounds__(256) void convert_split_f16(
    const float* __restrict__ src, ushort_t* __restrict__ dhi, ushort_t* __restrict__ dlo,
    int n)  // n % 4 == 0
{
    const int i = (blockIdx.x * 256 + threadIdx.x) * 4;
    if (i < n) {
        float4 v = *(const float4*)(src + i);
        ushort4 h, l;
        split_f16(v.x, h.x, l.x); split_f16(v.y, h.y, l.y);
        split_f16(v.z, h.z, l.z); split_f16(v.w, h.w, l.w);
        *(ushort4*)(dhi + i) = h;
        *(ushort4*)(dlo + i) = l;
    }
}

// ---------------- split-precision f16 MFMA GEMM: C = A @ W + bias (fp32 out) ----------------
// A = Ahi + Alo/2048 [M,K]; W given transposed: Whi/Wlo [N,K]. bias fp32 [N].
// C fp32 [M,N]. blockIdx.z selects weight/bias/output triple (gate fusion).
// Tile 128x128, BK=32, 4 waves, each wave 64x64 via 4x4 of 16x16x32_f16.
// Dual accumulators: accP = hi*hi, accQ = hi*lo + lo*hi; C = accP + accQ/2048.
__global__ __launch_bounds__(256, 2) void mfma_gemm3_split(
    const ushort_t* __restrict__ Ahi, const ushort_t* __restrict__ Alo,
    const ushort_t* __restrict__ Wh0, const ushort_t* __restrict__ Wl0,
    const ushort_t* __restrict__ Wh1, const ushort_t* __restrict__ Wl1,
    const ushort_t* __restrict__ Wh2, const ushort_t* __restrict__ Wl2,
    const float* __restrict__ b0, const float* __restrict__ b1, const float* __restrict__ b2,
    float* __restrict__ C0, float* __restrict__ C1, float* __restrict__ C2,
    int M, int N, int K)
{
    const int z = blockIdx.z;
    const ushort_t* __restrict__ Wh = (z == 0) ? Wh0 : (z == 1) ? Wh1 : Wh2;
    const ushort_t* __restrict__ Wl = (z == 0) ? Wl0 : (z == 1) ? Wl1 : Wl2;
    const float* __restrict__ bias  = (z == 0) ? b0  : (z == 1) ? b1  : b2;
    float* __restrict__ C           = (z == 0) ? C0  : (z == 1) ? C1  : C2;

    __shared__ __align__(16) ushort_t AsH[128 * 32];
    __shared__ __align__(16) ushort_t AsL[128 * 32];
    __shared__ __align__(16) ushort_t BsH[128 * 32];
    __shared__ __align__(16) ushort_t BsL[128 * 32];

    const int tid  = threadIdx.x;
    const int lane = tid & 63;
    const int wave = tid >> 6;
    const int quad = lane >> 4;
    const int l16  = lane & 15;
    const int wm   = wave >> 1;          // 0..1
    const int wn   = wave & 1;           // 0..1

    const int row0 = blockIdx.y * 128;
    const int col0 = blockIdx.x * 128;

    f32x4 accP[4][4] = {};
    f32x4 accQ[4][4] = {};

    for (int k0 = 0; k0 < K; k0 += 32) {
        // stage 4 tiles (128x32 f16 each): 512 16B-chunks/tile, 2 per thread per tile
#pragma unroll
        for (int i = 0; i < 2; ++i) {
            const int c  = tid + i * 256;       // 0..511
            const int r  = c >> 2;              // 0..127
            const int kc = c & 3;               // chunk-of-8 within BK
            const size_t ga = (size_t)(row0 + r) * K + k0 + kc * 8;
            const size_t gb = (size_t)(col0 + r) * K + k0 + kc * 8;
            gload_lds16(Ahi + ga, &AsH[c * 8]);
            gload_lds16(Alo + ga, &AsL[c * 8]);
            gload_lds16(Wh  + gb, &BsH[c * 8]);
            gload_lds16(Wl  + gb, &BsL[c * 8]);
        }
        __syncthreads();

        f16x8 ah[4], al[4], bh[4], bl[4];
#pragma unroll
        for (int i = 0; i < 4; ++i) {
            const int ro = (wm * 64 + i * 16 + l16) * 32 + quad * 8;
            ah[i] = *(const f16x8*)&AsH[ro];
            al[i] = *(const f16x8*)&AsL[ro];
        }
#pragma unroll
        for (int j = 0; j < 4; ++j) {
            const int ro = (wn * 64 + j * 16 + l16) * 32 + quad * 8;
            bh[j] = *(const f16x8*)&BsH[ro];
            bl[j] = *(const f16x8*)&BsL[ro];
        }

#pragma unroll
        for (int i = 0; i < 4; ++i)
#pragma unroll
            for (int j = 0; j < 4; ++j) {
                accP[i][j] = __builtin_amdgcn_mfma_f32_16x16x32_f16(ah[i], bh[j], accP[i][j], 0, 0, 0);
                accQ[i][j] = __builtin_amdgcn_mfma_f32_16x16x32_f16(ah[i], bl[j], accQ[i][j], 0, 0, 0);
                accQ[i][j] = __builtin_amdgcn_mfma_f32_16x16x32_f16(al[i], bh[j], accQ[i][j], 0, 0, 0);
            }
        __syncthreads();
    }

    // epilogue: C/D layout col = lane&15, row = quad*4 + reg
#pragma unroll
    for (int i = 0; i < 4; ++i) {
        const int row = row0 + wm * 64 + i * 16 + quad * 4;
#pragma unroll
        for (int j = 0; j < 4; ++j) {
            const int col = col0 + wn * 64 + j * 16 + l16;
            const float bv = bias[col];
#pragma unroll
            for (int r = 0; r < 4; ++r)
                C[(size_t)(row + r) * N + col] = accP[i][j][r] + accQ[i][j][r] * LO_INV + bv;
        }
    }
}

// ---------------- BRC scan (fp32 gates in, f16 hi/lo y out, fp32 recurrence) ----------------
__global__ __launch_bounds__(256) void brc_scan_split(
    const float* __restrict__ xa, const float* __restrict__ xc,
    const float* __restrict__ xh, const float* __restrict__ wa,
    const float* __restrict__ wc, const float* __restrict__ h_in,
    ushort_t* __restrict__ yhi, ushort_t* __restrict__ ylo,
    float* __restrict__ h_out, int T_c)
{
    const int gid = blockIdx.x * 256 + threadIdx.x;   // 0 .. BH/2-1
    const int idx = gid * 2;
    const int j = idx & (H_DIM - 1);
    float2 h = *(const float2*)(h_in + idx);
    const float wa0v = wa[j], wa1v = wa[j + 1];
    const float wc0v = wc[j], wc1v = wc[j + 1];

    float2 pa = *(const float2*)(xa + idx);
    float2 pc = *(const float2*)(xc + idx);
    float2 ph = *(const float2*)(xh + idx);

    for (int t = 0; t < T_c; ++t) {
        const float2 ca = pa, cc = pc, chv = ph;
        if (t + 1 < T_c) {
            const size_t nb = (size_t)(t + 1) * BH + idx;
            pa = *(const float2*)(xa + nb);
            pc = *(const float2*)(xc + nb);
            ph = *(const float2*)(xh + nb);
        }
        // element 0
        {
            const float a = 1.f + tanhf(ca.x + wa0v * h.x);
            const float zc = cc.x + wc0v * h.x;
            const float c = 1.f / (1.f + expf(-zc));
            h.x = c * h.x + (1.f - c) * tanhf(chv.x + a * h.x);
        }
        // element 1
        {
            const float a = 1.f + tanhf(ca.y + wa1v * h.y);
            const float zc = cc.y + wc1v * h.y;
            const float c = 1.f / (1.f + expf(-zc));
            h.y = c * h.y + (1.f - c) * tanhf(chv.y + a * h.y);
        }
        ushort_t h0h, h0l, h1h, h1l;
        split_f16(h.x, h0h, h0l);
        split_f16(h.y, h1h, h1l);
        const size_t ob = (size_t)t * BH + idx;
        *(uint_t*)(yhi + ob) = (uint_t)h0h | ((uint_t)h1h << 16);
        *(uint_t*)(ylo + ob) = (uint_t)h0l | ((uint_t)h1l << 16);
    }
    *(float2*)(h_out + idx) = h;
}

extern "C" void kernel_launch(void* const* d_in, const int* in_sizes, int n_in,
                              void* d_out, int out_size, void* d_ws, size_t ws_size,
                              hipStream_t stream) {
    const float* x    = (const float*)d_in[0];   // [S,B,IN]
    const float* h0   = (const float*)d_in[1];   // [L,B,H]
    const float* Ua0  = (const float*)d_in[2];
    const float* Uc0  = (const float*)d_in[3];
    const float* Uh0  = (const float*)d_in[4];
    const float* wa0  = (const float*)d_in[5];
    const float* wc0  = (const float*)d_in[6];
    const float* ba0  = (const float*)d_in[7];
    const float* bc0  = (const float*)d_in[8];
    const float* bh0  = (const float*)d_in[9];
    const float* Ua1  = (const float*)d_in[10];
    const float* Uc1  = (const float*)d_in[11];
    const float* Uh1  = (const float*)d_in[12];
    const float* wa1  = (const float*)d_in[13];
    const float* wc1  = (const float*)d_in[14];
    const float* ba1  = (const float*)d_in[15];
    const float* bc1  = (const float*)d_in[16];
    const float* bh1  = (const float*)d_in[17];
    const float* Wdec = (const float*)d_in[18];
    const float* bdec = (const float*)d_in[19];

    float* outF = (float*)d_out;
    float* out_seq  = outF;                                   // [S,B,OUT]
    float* h_last0  = outF + (size_t)S_DIM * B_DIM * OUT_DIM; // [B,H]
    float* h_last1  = h_last0 + BH;                           // [B,H]

    // ---- workspace carve-up ----
    char* wsb = (char*)d_ws;
    size_t off = 0;
    auto alloc = [&](size_t bytes) -> void* {
        void* p = wsb + off;
        off += (bytes + 255) & ~(size_t)255;
        return p;
    };
    const size_t szL0 = (size_t)IN_DIM * H_DIM;   // 524288
    const size_t szL1 = (size_t)H_DIM * H_DIM;    // 1048576
    const size_t szD  = (size_t)H_DIM * OUT_DIM;  // 524288
    ushort_t *Wa0h = (ushort_t*)alloc(szL0 * 2), *Wa0l = (ushort_t*)alloc(szL0 * 2);
    ushort_t *Wc0h = (ushort_t*)alloc(szL0 * 2), *Wc0l = (ushort_t*)alloc(szL0 * 2);
    ushort_t *Wh0h = (ushort_t*)alloc(szL0 * 2), *Wh0l = (ushort_t*)alloc(szL0 * 2);
    ushort_t *Wa1h = (ushort_t*)alloc(szL1 * 2), *Wa1l = (ushort_t*)alloc(szL1 * 2);
    ushort_t *Wc1h = (ushort_t*)alloc(szL1 * 2), *Wc1l = (ushort_t*)alloc(szL1 * 2);
    ushort_t *Wh1h = (ushort_t*)alloc(szL1 * 2), *Wh1l = (ushort_t*)alloc(szL1 * 2);
    ushort_t *Wdh  = (ushort_t*)alloc(szD * 2),  *Wdl  = (ushort_t*)alloc(szD * 2);

    // Per-chunk bytes: x hi/lo (T*B*IN f16 x2) + 3 fp32 gate planes (T*BH)
    //                 + y0 hi/lo + y1 hi/lo (T*BH f16 x4)
    // = T * (2*B*IN*2 + 3*BH*4 + 4*BH*2)
    const size_t perT = (size_t)2 * B_DIM * IN_DIM * 2 + (size_t)3 * BH * 4 + (size_t)4 * BH * 2;
    int T_c = 512;
    while (T_c > 1 && off + (size_t)T_c * perT + 4096 > ws_size) T_c >>= 1;
    const size_t chunk_elems = (size_t)T_c * BH;
    const size_t xchunk_elems = (size_t)T_c * B_DIM * IN_DIM;

    ushort_t* xhib = (ushort_t*)alloc(xchunk_elems * 2);
    ushort_t* xlob = (ushort_t*)alloc(xchunk_elems * 2);
    float* g_a = (float*)alloc(chunk_elems * 4);
    float* g_c = (float*)alloc(chunk_elems * 4);
    float* g_h = (float*)alloc(chunk_elems * 4);
    ushort_t* y0h = (ushort_t*)alloc(chunk_elems * 2);
    ushort_t* y0l = (ushort_t*)alloc(chunk_elems * 2);
    ushort_t* y1h = (ushort_t*)alloc(chunk_elems * 2);
    ushort_t* y1l = (ushort_t*)alloc(chunk_elems * 2);

    const int n_chunks = S_DIM / T_c;
    const int Mc = T_c * B_DIM;

    // ---- one-time per call: weight transpose+split ----
    transpose_split_f16<<<dim3(H_DIM / 32, IN_DIM / 32), 256, 0, stream>>>(Ua0, Wa0h, Wa0l, IN_DIM, H_DIM);
    transpose_split_f16<<<dim3(H_DIM / 32, IN_DIM / 32), 256, 0, stream>>>(Uc0, Wc0h, Wc0l, IN_DIM, H_DIM);
    transpose_split_f16<<<dim3(H_DIM / 32, IN_DIM / 32), 256, 0, stream>>>(Uh0, Wh0h, Wh0l, IN_DIM, H_DIM);
    transpose_split_f16<<<dim3(H_DIM / 32, H_DIM / 32), 256, 0, stream>>>(Ua1, Wa1h, Wa1l, H_DIM, H_DIM);
    transpose_split_f16<<<dim3(H_DIM / 32, H_DIM / 32), 256, 0, stream>>>(Uc1, Wc1h, Wc1l, H_DIM, H_DIM);
    transpose_split_f16<<<dim3(H_DIM / 32, H_DIM / 32), 256, 0, stream>>>(Uh1, Wh1h, Wh1l, H_DIM, H_DIM);
    transpose_split_f16<<<dim3(OUT_DIM / 32, H_DIM / 32), 256, 0, stream>>>(Wdec, Wdh, Wdl, H_DIM, OUT_DIM);

    dim3 blk(256);
    dim3 grid_g(H_DIM / 128, Mc / 128, 3);
    dim3 grid_d(OUT_DIM / 128, Mc / 128, 1);
    dim3 grid_scan(BH / 2 / 256);

    for (int ci = 0; ci < n_chunks; ++ci) {
        const float* x_chunk = x + (size_t)ci * Mc * IN_DIM;
        float* out_chunk = out_seq + (size_t)ci * Mc * OUT_DIM;

        // split x chunk -> hi/lo f16 planes
        convert_split_f16<<<dim3((int)(xchunk_elems / 4 / 256)), blk, 0, stream>>>(
            x_chunk, xhib, xlob, (int)xchunk_elems);

        // layer 0 gates: x @ U{a,c,h}0 + b -> fp32 gate buffers
        mfma_gemm3_split<<<grid_g, blk, 0, stream>>>(
            xhib, xlob, Wa0h, Wa0l, Wc0h, Wc0l, Wh0h, Wh0l,
            ba0, bc0, bh0, g_a, g_c, g_h, Mc, H_DIM, IN_DIM);
        brc_scan_split<<<grid_scan, blk, 0, stream>>>(
            g_a, g_c, g_h, wa0, wc0, (ci == 0) ? h0 : h_last0, y0h, y0l, h_last0, T_c);

        // layer 1 gates: y0 @ U{a,c,h}1 + b
        mfma_gemm3_split<<<grid_g, blk, 0, stream>>>(
            y0h, y0l, Wa1h, Wa1l, Wc1h, Wc1l, Wh1h, Wh1l,
            ba1, bc1, bh1, g_a, g_c, g_h, Mc, H_DIM, H_DIM);
        brc_scan_split<<<grid_scan, blk, 0, stream>>>(
            g_a, g_c, g_h, wa1, wc1, (ci == 0) ? (h0 + BH) : h_last1, y1h, y1l, h_last1, T_c);

        // decoder: y1 @ Wdec + bdec -> fp32 out
        mfma_gemm3_split<<<grid_d, blk, 0, stream>>>(
            y1h, y1l, Wdh, Wdl, Wdh, Wdl, Wdh, Wdl,
            bdec, bdec, bdec, out_chunk, out_chunk, out_chunk, Mc, OUT_DIM, H_DIM);
    }
}

// Round 6
// 1771.926 us; speedup vs baseline: 2.7691x; 1.2084x over previous
//
#include <hip/hip_runtime.h>
#include <math.h>

// Problem dims (fixed by reference)
#define S_DIM 512
#define B_DIM 64
#define IN_DIM 512
#define H_DIM 1024
#define OUT_DIM 512
#define BH (B_DIM * H_DIM)      // 65536

typedef unsigned short ushort_t;
typedef unsigned int uint_t;
using f32x4 = __attribute__((ext_vector_type(4))) float;
using f16x8 = __attribute__((ext_vector_type(8))) _Float16;  // 8 f16 (4 VGPRs)

#define LO_SCALE 2048.0f          // 2^11
#define LO_INV   (1.0f / 2048.0f)

// ---- fp32 -> f16 hi/lo split: x ~= hi + lo/2048 (lo holds residual * 2^11) ----
__device__ __forceinline__ void split_f16(float v, ushort_t& hi, ushort_t& lo) {
    _Float16 h = (_Float16)v;
    float r = (v - (float)h) * LO_SCALE;
    _Float16 l = (_Float16)r;
    hi = __builtin_bit_cast(ushort_t, h);
    lo = __builtin_bit_cast(ushort_t, l);
}

// ---- fast transcendentals (v_exp_f32 / v_rcp_f32 based) ----
__device__ __forceinline__ float frcp(float x) { return __builtin_amdgcn_rcpf(x); }
__device__ __forceinline__ float fsig(float z) { return frcp(1.f + __expf(-z)); }
__device__ __forceinline__ float ftanh(float z) { return 1.f - 2.f * frcp(1.f + __expf(2.f * z)); }

__device__ __forceinline__ void gload_lds16(const ushort_t* g, ushort_t* l) {
    __builtin_amdgcn_global_load_lds(
        (const __attribute__((address_space(1))) void*)g,
        (__attribute__((address_space(3))) void*)l, 16, 0, 0);
}

// ---------------- weight transpose + split: W[K,N] f32 -> Whi/Wlo [N,K] f16 ----------------
__global__ __launch_bounds__(256) void transpose_split_f16(
    const float* __restrict__ W, ushort_t* __restrict__ Whi, ushort_t* __restrict__ Wlo,
    int K, int N)
{
    __shared__ float tile[32][33];
    const int k0 = blockIdx.y * 32, n0 = blockIdx.x * 32;
    const int tx = threadIdx.x & 31, ty = threadIdx.x >> 5;   // ty 0..7
#pragma unroll
    for (int r = 0; r < 32; r += 8)
        tile[ty + r][tx] = W[(size_t)(k0 + ty + r) * N + n0 + tx];
    __syncthreads();
#pragma unroll
    for (int r = 0; r < 32; r += 8) {
        ushort_t hi, lo;
        split_f16(tile[tx][ty + r], hi, lo);
        const size_t o = (size_t)(n0 + ty + r) * K + k0 + tx;
        Whi[o] = hi;
        Wlo[o] = lo;
    }
}

// ---------------- f32 -> f16 hi/lo split (activations, contiguous) ----------------
__global__ __launch_bounds__(256) void convert_split_f16(
    const float* __restrict__ src, ushort_t* __restrict__ dhi, ushort_t* __restrict__ dlo,
    int n)  // n % 4 == 0
{
    const int i = (blockIdx.x * 256 + threadIdx.x) * 4;
    if (i < n) {
        float4 v = *(const float4*)(src + i);
        ushort4 h, l;
        split_f16(v.x, h.x, l.x); split_f16(v.y, h.y, l.y);
        split_f16(v.z, h.z, l.z); split_f16(v.w, h.w, l.w);
        *(ushort4*)(dhi + i) = h;
        *(ushort4*)(dlo + i) = l;
    }
}

// ---------------- split-precision f16 MFMA GEMM: C = A @ W + bias (fp32 out) ----------------
// A = Ahi + Alo/2048 [M,K]; W given transposed: Whi/Wlo [N,K]. bias fp32 [N].
// C fp32 [M,N]. blockIdx.z selects weight/bias/output triple (gate fusion).
// Tile 128x128, BK=32, 4 waves, each wave 64x64 via 4x4 of 16x16x32_f16.
// Dual accumulators: accP = hi*hi, accQ = hi*lo + lo*hi; C = accP + accQ/2048.
__global__ __launch_bounds__(256, 2) void mfma_gemm3_split(
    const ushort_t* __restrict__ Ahi, const ushort_t* __restrict__ Alo,
    const ushort_t* __restrict__ Wh0, const ushort_t* __restrict__ Wl0,
    const ushort_t* __restrict__ Wh1, const ushort_t* __restrict__ Wl1,
    const ushort_t* __restrict__ Wh2, const ushort_t* __restrict__ Wl2,
    const float* __restrict__ b0, const float* __restrict__ b1, const float* __restrict__ b2,
    float* __restrict__ C0, float* __restrict__ C1, float* __restrict__ C2,
    int M, int N, int K)
{
    const int z = blockIdx.z;
    const ushort_t* __restrict__ Wh = (z == 0) ? Wh0 : (z == 1) ? Wh1 : Wh2;
    const ushort_t* __restrict__ Wl = (z == 0) ? Wl0 : (z == 1) ? Wl1 : Wl2;
    const float* __restrict__ bias  = (z == 0) ? b0  : (z == 1) ? b1  : b2;
    float* __restrict__ C           = (z == 0) ? C0  : (z == 1) ? C1  : C2;

    __shared__ __align__(16) ushort_t AsH[128 * 32];
    __shared__ __align__(16) ushort_t AsL[128 * 32];
    __shared__ __align__(16) ushort_t BsH[128 * 32];
    __shared__ __align__(16) ushort_t BsL[128 * 32];

    const int tid  = threadIdx.x;
    const int lane = tid & 63;
    const int wave = tid >> 6;
    const int quad = lane >> 4;
    const int l16  = lane & 15;
    const int wm   = wave >> 1;          // 0..1
    const int wn   = wave & 1;           // 0..1

    const int row0 = blockIdx.y * 128;
    const int col0 = blockIdx.x * 128;

    f32x4 accP[4][4] = {};
    f32x4 accQ[4][4] = {};

    for (int k0 = 0; k0 < K; k0 += 32) {
        // stage 4 tiles (128x32 f16 each): 512 16B-chunks/tile, 2 per thread per tile
#pragma unroll
        for (int i = 0; i < 2; ++i) {
            const int c  = tid + i * 256;       // 0..511
            const int r  = c >> 2;              // 0..127
            const int kc = c & 3;               // chunk-of-8 within BK
            const size_t ga = (size_t)(row0 + r) * K + k0 + kc * 8;
            const size_t gb = (size_t)(col0 + r) * K + k0 + kc * 8;
            gload_lds16(Ahi + ga, &AsH[c * 8]);
            gload_lds16(Alo + ga, &AsL[c * 8]);
            gload_lds16(Wh  + gb, &BsH[c * 8]);
            gload_lds16(Wl  + gb, &BsL[c * 8]);
        }
        __syncthreads();

        f16x8 ah[4], al[4], bh[4], bl[4];
#pragma unroll
        for (int i = 0; i < 4; ++i) {
            const int ro = (wm * 64 + i * 16 + l16) * 32 + quad * 8;
            ah[i] = *(const f16x8*)&AsH[ro];
            al[i] = *(const f16x8*)&AsL[ro];
        }
#pragma unroll
        for (int j = 0; j < 4; ++j) {
            const int ro = (wn * 64 + j * 16 + l16) * 32 + quad * 8;
            bh[j] = *(const f16x8*)&BsH[ro];
            bl[j] = *(const f16x8*)&BsL[ro];
        }

#pragma unroll
        for (int i = 0; i < 4; ++i)
#pragma unroll
            for (int j = 0; j < 4; ++j) {
                accP[i][j] = __builtin_amdgcn_mfma_f32_16x16x32_f16(ah[i], bh[j], accP[i][j], 0, 0, 0);
                accQ[i][j] = __builtin_amdgcn_mfma_f32_16x16x32_f16(ah[i], bl[j], accQ[i][j], 0, 0, 0);
                accQ[i][j] = __builtin_amdgcn_mfma_f32_16x16x32_f16(al[i], bh[j], accQ[i][j], 0, 0, 0);
            }
        __syncthreads();
    }

    // epilogue: C/D layout col = lane&15, row = quad*4 + reg
#pragma unroll
    for (int i = 0; i < 4; ++i) {
        const int row = row0 + wm * 64 + i * 16 + quad * 4;
#pragma unroll
        for (int j = 0; j < 4; ++j) {
            const int col = col0 + wn * 64 + j * 16 + l16;
            const float bv = bias[col];
#pragma unroll
            for (int r = 0; r < 4; ++r)
                C[(size_t)(row + r) * N + col] = accP[i][j][r] + accQ[i][j][r] * LO_INV + bv;
        }
    }
}

// ---------------- single-precision f16 MFMA GEMM (decoder): C = A @ W + bias ----------------
// Decoder error is not amplified by the recurrence -> f16 is plenty.
__global__ __launch_bounds__(256, 2) void mfma_gemm_dec(
    const ushort_t* __restrict__ A, const ushort_t* __restrict__ Wt,
    const float* __restrict__ bias, float* __restrict__ C,
    int M, int N, int K)
{
    __shared__ __align__(16) ushort_t As[128 * 32];
    __shared__ __align__(16) ushort_t Bs[128 * 32];

    const int tid  = threadIdx.x;
    const int lane = tid & 63;
    const int wave = tid >> 6;
    const int quad = lane >> 4;
    const int l16  = lane & 15;
    const int wm   = wave >> 1;
    const int wn   = wave & 1;

    const int row0 = blockIdx.y * 128;
    const int col0 = blockIdx.x * 128;

    f32x4 acc[4][4] = {};

    for (int k0 = 0; k0 < K; k0 += 32) {
#pragma unroll
        for (int i = 0; i < 2; ++i) {
            const int c  = tid + i * 256;
            const int r  = c >> 2;
            const int kc = c & 3;
            gload_lds16(A  + (size_t)(row0 + r) * K + k0 + kc * 8, &As[c * 8]);
            gload_lds16(Wt + (size_t)(col0 + r) * K + k0 + kc * 8, &Bs[c * 8]);
        }
        __syncthreads();

        f16x8 af[4], bf[4];
#pragma unroll
        for (int i = 0; i < 4; ++i)
            af[i] = *(const f16x8*)&As[(wm * 64 + i * 16 + l16) * 32 + quad * 8];
#pragma unroll
        for (int j = 0; j < 4; ++j)
            bf[j] = *(const f16x8*)&Bs[(wn * 64 + j * 16 + l16) * 32 + quad * 8];

#pragma unroll
        for (int i = 0; i < 4; ++i)
#pragma unroll
            for (int j = 0; j < 4; ++j)
                acc[i][j] = __builtin_amdgcn_mfma_f32_16x16x32_f16(af[i], bf[j], acc[i][j], 0, 0, 0);
        __syncthreads();
    }

#pragma unroll
    for (int i = 0; i < 4; ++i) {
        const int row = row0 + wm * 64 + i * 16 + quad * 4;
#pragma unroll
        for (int j = 0; j < 4; ++j) {
            const int col = col0 + wn * 64 + j * 16 + l16;
            const float bv = bias[col];
#pragma unroll
            for (int r = 0; r < 4; ++r)
                C[(size_t)(row + r) * N + col] = acc[i][j][r] + bv;
        }
    }
}

// ---------------- BRC scan: 1 elem/thread, 4-deep prefetch, fast transcendentals ----------------
// fp32 gates in, y out as f16 hi (+ optional lo plane), fp32 recurrence.
template <bool WRITE_LO>
__global__ __launch_bounds__(256) void brc_scan_v2(
    const float* __restrict__ xa, const float* __restrict__ xc,
    const float* __restrict__ xh, const float* __restrict__ wa,
    const float* __restrict__ wc, const float* __restrict__ h_in,
    ushort_t* __restrict__ yhi, ushort_t* __restrict__ ylo,
    float* __restrict__ h_out, int T_c)
{
    const int idx = blockIdx.x * 256 + threadIdx.x;   // 0..BH-1
    const int j = idx & (H_DIM - 1);
    float h = h_in[idx];
    const float waj = wa[j], wcj = wc[j];

    float pa[4], pc[4], ph[4];
#pragma unroll
    for (int d = 0; d < 4; ++d) {
        const int dd = (d < T_c) ? d : 0;
        const size_t b = (size_t)dd * BH + idx;
        pa[d] = xa[b]; pc[d] = xc[b]; ph[d] = xh[b];
    }

#pragma unroll 4
    for (int t = 0; t < T_c; ++t) {
        const int s = t & 3;
        const float ca = pa[s], cc = pc[s], ch = ph[s];
        const int tn = t + 4;
        if (tn < T_c) {
            const size_t b = (size_t)tn * BH + idx;
            pa[s] = xa[b]; pc[s] = xc[b]; ph[s] = xh[b];
        }
        const float a = 1.f + ftanh(ca + waj * h);
        const float c = fsig(cc + wcj * h);
        h = c * h + (1.f - c) * ftanh(ch + a * h);

        ushort_t hh, hl;
        split_f16(h, hh, hl);
        const size_t ob = (size_t)t * BH + idx;
        yhi[ob] = hh;
        if (WRITE_LO) ylo[ob] = hl;
    }
    h_out[idx] = h;
}

extern "C" void kernel_launch(void* const* d_in, const int* in_sizes, int n_in,
                              void* d_out, int out_size, void* d_ws, size_t ws_size,
                              hipStream_t stream) {
    const float* x    = (const float*)d_in[0];   // [S,B,IN]
    const float* h0   = (const float*)d_in[1];   // [L,B,H]
    const float* Ua0  = (const float*)d_in[2];
    const float* Uc0  = (const float*)d_in[3];
    const float* Uh0  = (const float*)d_in[4];
    const float* wa0  = (const float*)d_in[5];
    const float* wc0  = (const float*)d_in[6];
    const float* ba0  = (const float*)d_in[7];
    const float* bc0  = (const float*)d_in[8];
    const float* bh0  = (const float*)d_in[9];
    const float* Ua1  = (const float*)d_in[10];
    const float* Uc1  = (const float*)d_in[11];
    const float* Uh1  = (const float*)d_in[12];
    const float* wa1  = (const float*)d_in[13];
    const float* wc1  = (const float*)d_in[14];
    const float* ba1  = (const float*)d_in[15];
    const float* bc1  = (const float*)d_in[16];
    const float* bh1  = (const float*)d_in[17];
    const float* Wdec = (const float*)d_in[18];
    const float* bdec = (const float*)d_in[19];

    float* outF = (float*)d_out;
    float* out_seq  = outF;                                   // [S,B,OUT]
    float* h_last0  = outF + (size_t)S_DIM * B_DIM * OUT_DIM; // [B,H]
    float* h_last1  = h_last0 + BH;                           // [B,H]

    // ---- workspace carve-up ----
    char* wsb = (char*)d_ws;
    size_t off = 0;
    auto alloc = [&](size_t bytes) -> void* {
        void* p = wsb + off;
        off += (bytes + 255) & ~(size_t)255;
        return p;
    };
    const size_t szL0 = (size_t)IN_DIM * H_DIM;
    const size_t szL1 = (size_t)H_DIM * H_DIM;
    const size_t szD  = (size_t)H_DIM * OUT_DIM;
    ushort_t *Wa0h = (ushort_t*)alloc(szL0 * 2), *Wa0l = (ushort_t*)alloc(szL0 * 2);
    ushort_t *Wc0h = (ushort_t*)alloc(szL0 * 2), *Wc0l = (ushort_t*)alloc(szL0 * 2);
    ushort_t *Wh0h = (ushort_t*)alloc(szL0 * 2), *Wh0l = (ushort_t*)alloc(szL0 * 2);
    ushort_t *Wa1h = (ushort_t*)alloc(szL1 * 2), *Wa1l = (ushort_t*)alloc(szL1 * 2);
    ushort_t *Wc1h = (ushort_t*)alloc(szL1 * 2), *Wc1l = (ushort_t*)alloc(szL1 * 2);
    ushort_t *Wh1h = (ushort_t*)alloc(szL1 * 2), *Wh1l = (ushort_t*)alloc(szL1 * 2);
    ushort_t *Wdh  = (ushort_t*)alloc(szD * 2),  *Wdl  = (ushort_t*)alloc(szD * 2);

    // Per-chunk bytes: x hi/lo + 3 fp32 gate planes + y0 hi/lo + y1 hi (no y1 lo)
    const size_t perT = (size_t)2 * B_DIM * IN_DIM * 2 + (size_t)3 * BH * 4 + (size_t)3 * BH * 2;
    int T_c = 512;
    while (T_c > 1 && off + (size_t)T_c * perT + 4096 > ws_size) T_c >>= 1;
    const size_t chunk_elems = (size_t)T_c * BH;
    const size_t xchunk_elems = (size_t)T_c * B_DIM * IN_DIM;

    ushort_t* xhib = (ushort_t*)alloc(xchunk_elems * 2);
    ushort_t* xlob = (ushort_t*)alloc(xchunk_elems * 2);
    float* g_a = (float*)alloc(chunk_elems * 4);
    float* g_c = (float*)alloc(chunk_elems * 4);
    float* g_h = (float*)alloc(chunk_elems * 4);
    ushort_t* y0h = (ushort_t*)alloc(chunk_elems * 2);
    ushort_t* y0l = (ushort_t*)alloc(chunk_elems * 2);
    ushort_t* y1h = (ushort_t*)alloc(chunk_elems * 2);

    const int n_chunks = S_DIM / T_c;
    const int Mc = T_c * B_DIM;

    // ---- one-time per call: weight transpose+split ----
    transpose_split_f16<<<dim3(H_DIM / 32, IN_DIM / 32), 256, 0, stream>>>(Ua0, Wa0h, Wa0l, IN_DIM, H_DIM);
    transpose_split_f16<<<dim3(H_DIM / 32, IN_DIM / 32), 256, 0, stream>>>(Uc0, Wc0h, Wc0l, IN_DIM, H_DIM);
    transpose_split_f16<<<dim3(H_DIM / 32, IN_DIM / 32), 256, 0, stream>>>(Uh0, Wh0h, Wh0l, IN_DIM, H_DIM);
    transpose_split_f16<<<dim3(H_DIM / 32, H_DIM / 32), 256, 0, stream>>>(Ua1, Wa1h, Wa1l, H_DIM, H_DIM);
    transpose_split_f16<<<dim3(H_DIM / 32, H_DIM / 32), 256, 0, stream>>>(Uc1, Wc1h, Wc1l, H_DIM, H_DIM);
    transpose_split_f16<<<dim3(H_DIM / 32, H_DIM / 32), 256, 0, stream>>>(Uh1, Wh1h, Wh1l, H_DIM, H_DIM);
    transpose_split_f16<<<dim3(OUT_DIM / 32, H_DIM / 32), 256, 0, stream>>>(Wdec, Wdh, Wdl, H_DIM, OUT_DIM);

    dim3 blk(256);
    dim3 grid_g(H_DIM / 128, Mc / 128, 3);
    dim3 grid_d(OUT_DIM / 128, Mc / 128, 1);
    dim3 grid_scan(BH / 256);

    for (int ci = 0; ci < n_chunks; ++ci) {
        const float* x_chunk = x + (size_t)ci * Mc * IN_DIM;
        float* out_chunk = out_seq + (size_t)ci * Mc * OUT_DIM;

        // split x chunk -> hi/lo f16 planes
        convert_split_f16<<<dim3((int)(xchunk_elems / 4 / 256)), blk, 0, stream>>>(
            x_chunk, xhib, xlob, (int)xchunk_elems);

        // layer 0 gates: x @ U{a,c,h}0 + b -> fp32 gate buffers
        mfma_gemm3_split<<<grid_g, blk, 0, stream>>>(
            xhib, xlob, Wa0h, Wa0l, Wc0h, Wc0l, Wh0h, Wh0l,
            ba0, bc0, bh0, g_a, g_c, g_h, Mc, H_DIM, IN_DIM);
        brc_scan_v2<true><<<grid_scan, blk, 0, stream>>>(
            g_a, g_c, g_h, wa0, wc0, (ci == 0) ? h0 : h_last0, y0h, y0l, h_last0, T_c);

        // layer 1 gates: y0 @ U{a,c,h}1 + b
        mfma_gemm3_split<<<grid_g, blk, 0, stream>>>(
            y0h, y0l, Wa1h, Wa1l, Wc1h, Wc1l, Wh1h, Wh1l,
            ba1, bc1, bh1, g_a, g_c, g_h, Mc, H_DIM, H_DIM);
        brc_scan_v2<false><<<grid_scan, blk, 0, stream>>>(
            g_a, g_c, g_h, wa1, wc1, (ci == 0) ? (h0 + BH) : h_last1, y1h, nullptr, h_last1, T_c);

        // decoder: y1(hi) @ Wdec + bdec -> fp32 out (single f16 MFMA is enough here)
        mfma_gemm_dec<<<grid_d, blk, 0, stream>>>(
            y1h, Wdh, bdec, out_chunk, Mc, OUT_DIM, H_DIM);
    }
}

// Round 7
// 1639.181 us; speedup vs baseline: 2.9934x; 1.0810x over previous
//
#include <hip/hip_runtime.h>
#include <math.h>

// Problem dims (fixed by reference)
#define S_DIM 512
#define B_DIM 64
#define IN_DIM 512
#define H_DIM 1024
#define OUT_DIM 512
#define BH (B_DIM * H_DIM)      // 65536

typedef unsigned short ushort_t;
typedef unsigned int uint_t;
using f32x4 = __attribute__((ext_vector_type(4))) float;
using f16x8 = __attribute__((ext_vector_type(8))) _Float16;  // 8 f16 (4 VGPRs)

#define LO_SCALE 2048.0f          // 2^11
#define LO_INV   (1.0f / 2048.0f)

// ---- fp32 -> f16 hi/lo split: x ~= hi + lo/2048 (lo holds residual * 2^11) ----
__device__ __forceinline__ void split_f16(float v, ushort_t& hi, ushort_t& lo) {
    _Float16 h = (_Float16)v;
    float r = (v - (float)h) * LO_SCALE;
    _Float16 l = (_Float16)r;
    hi = __builtin_bit_cast(ushort_t, h);
    lo = __builtin_bit_cast(ushort_t, l);
}

// ---- fast transcendentals (v_exp_f32 / v_rcp_f32 based) ----
__device__ __forceinline__ float frcp(float x) { return __builtin_amdgcn_rcpf(x); }
__device__ __forceinline__ float fsig(float z) { return frcp(1.f + __expf(-z)); }
__device__ __forceinline__ float ftanh(float z) { return 1.f - 2.f * frcp(1.f + __expf(2.f * z)); }

__device__ __forceinline__ void gload_lds16(const ushort_t* g, ushort_t* l) {
    __builtin_amdgcn_global_load_lds(
        (const __attribute__((address_space(1))) void*)g,
        (__attribute__((address_space(3))) void*)l, 16, 0, 0);
}

// ---------------- weight transpose + split: W[K,N] f32 -> Whi/Wlo [N,K] f16 ----------------
__global__ __launch_bounds__(256) void transpose_split_f16(
    const float* __restrict__ W, ushort_t* __restrict__ Whi, ushort_t* __restrict__ Wlo,
    int K, int N)
{
    __shared__ float tile[32][33];
    const int k0 = blockIdx.y * 32, n0 = blockIdx.x * 32;
    const int tx = threadIdx.x & 31, ty = threadIdx.x >> 5;   // ty 0..7
#pragma unroll
    for (int r = 0; r < 32; r += 8)
        tile[ty + r][tx] = W[(size_t)(k0 + ty + r) * N + n0 + tx];
    __syncthreads();
#pragma unroll
    for (int r = 0; r < 32; r += 8) {
        ushort_t hi, lo;
        split_f16(tile[tx][ty + r], hi, lo);
        const size_t o = (size_t)(n0 + ty + r) * K + k0 + tx;
        Whi[o] = hi;
        Wlo[o] = lo;
    }
}

// ---------------- f32 -> f16 hi/lo split (activations, contiguous) ----------------
__global__ __launch_bounds__(256) void convert_split_f16(
    const float* __restrict__ src, ushort_t* __restrict__ dhi, ushort_t* __restrict__ dlo,
    int n)  // n % 4 == 0
{
    const int i = (blockIdx.x * 256 + threadIdx.x) * 4;
    if (i < n) {
        float4 v = *(const float4*)(src + i);
        ushort4 h, l;
        split_f16(v.x, h.x, l.x); split_f16(v.y, h.y, l.y);
        split_f16(v.z, h.z, l.z); split_f16(v.w, h.w, l.w);
        *(ushort4*)(dhi + i) = h;
        *(ushort4*)(dlo + i) = l;
    }
}

// ---------------- split-precision f16 MFMA GEMM: C = A @ W + bias (fp32 out) ----------------
// A = Ahi + Alo/2048 [M,K]; W transposed: Whi/Wlo [N,K]. bias fp32 [N]. C fp32 [M,N].
// 1D swizzled grid: M-strip OUTER, (gate, N-block) INNER -> all 3*NB consumers of an
// A-strip dispatch adjacently and hit L2 instead of re-fetching from HBM.
// Tile 128x128, BK=32, 4 waves; dual accumulators accP (hi*hi), accQ (cross terms).
__global__ __launch_bounds__(256, 2) void mfma_gemm3_split(
    const ushort_t* __restrict__ Ahi, const ushort_t* __restrict__ Alo,
    const ushort_t* __restrict__ Wh0, const ushort_t* __restrict__ Wl0,
    const ushort_t* __restrict__ Wh1, const ushort_t* __restrict__ Wl1,
    const ushort_t* __restrict__ Wh2, const ushort_t* __restrict__ Wl2,
    const float* __restrict__ b0, const float* __restrict__ b1, const float* __restrict__ b2,
    float* __restrict__ C0, float* __restrict__ C1, float* __restrict__ C2,
    int M, int N, int K)
{
    const int NB = N >> 7;                 // N-blocks
    const int inner = blockIdx.x % (3 * NB);
    const int mb = blockIdx.x / (3 * NB);
    const int nb = inner % NB;
    const int z  = inner / NB;

    const ushort_t* __restrict__ Wh = (z == 0) ? Wh0 : (z == 1) ? Wh1 : Wh2;
    const ushort_t* __restrict__ Wl = (z == 0) ? Wl0 : (z == 1) ? Wl1 : Wl2;
    const float* __restrict__ bias  = (z == 0) ? b0  : (z == 1) ? b1  : b2;
    float* __restrict__ C           = (z == 0) ? C0  : (z == 1) ? C1  : C2;

    __shared__ __align__(16) ushort_t AsH[128 * 32];
    __shared__ __align__(16) ushort_t AsL[128 * 32];
    __shared__ __align__(16) ushort_t BsH[128 * 32];
    __shared__ __align__(16) ushort_t BsL[128 * 32];

    const int tid  = threadIdx.x;
    const int lane = tid & 63;
    const int wave = tid >> 6;
    const int quad = lane >> 4;
    const int l16  = lane & 15;
    const int wm   = wave >> 1;          // 0..1
    const int wn   = wave & 1;           // 0..1

    const int row0 = mb * 128;
    const int col0 = nb * 128;

    f32x4 accP[4][4] = {};
    f32x4 accQ[4][4] = {};

    for (int k0 = 0; k0 < K; k0 += 32) {
#pragma unroll
        for (int i = 0; i < 2; ++i) {
            const int c  = tid + i * 256;       // 0..511
            const int r  = c >> 2;              // 0..127
            const int kc = c & 3;               // chunk-of-8 within BK
            const size_t ga = (size_t)(row0 + r) * K + k0 + kc * 8;
            const size_t gb = (size_t)(col0 + r) * K + k0 + kc * 8;
            gload_lds16(Ahi + ga, &AsH[c * 8]);
            gload_lds16(Alo + ga, &AsL[c * 8]);
            gload_lds16(Wh  + gb, &BsH[c * 8]);
            gload_lds16(Wl  + gb, &BsL[c * 8]);
        }
        __syncthreads();

        f16x8 ah[4], al[4], bh[4], bl[4];
#pragma unroll
        for (int i = 0; i < 4; ++i) {
            const int ro = (wm * 64 + i * 16 + l16) * 32 + quad * 8;
            ah[i] = *(const f16x8*)&AsH[ro];
            al[i] = *(const f16x8*)&AsL[ro];
        }
#pragma unroll
        for (int j = 0; j < 4; ++j) {
            const int ro = (wn * 64 + j * 16 + l16) * 32 + quad * 8;
            bh[j] = *(const f16x8*)&BsH[ro];
            bl[j] = *(const f16x8*)&BsL[ro];
        }

#pragma unroll
        for (int i = 0; i < 4; ++i)
#pragma unroll
            for (int j = 0; j < 4; ++j) {
                accP[i][j] = __builtin_amdgcn_mfma_f32_16x16x32_f16(ah[i], bh[j], accP[i][j], 0, 0, 0);
                accQ[i][j] = __builtin_amdgcn_mfma_f32_16x16x32_f16(ah[i], bl[j], accQ[i][j], 0, 0, 0);
                accQ[i][j] = __builtin_amdgcn_mfma_f32_16x16x32_f16(al[i], bh[j], accQ[i][j], 0, 0, 0);
            }
        __syncthreads();
    }

    // epilogue: C/D layout col = lane&15, row = quad*4 + reg
#pragma unroll
    for (int i = 0; i < 4; ++i) {
        const int row = row0 + wm * 64 + i * 16 + quad * 4;
#pragma unroll
        for (int j = 0; j < 4; ++j) {
            const int col = col0 + wn * 64 + j * 16 + l16;
            const float bv = bias[col];
#pragma unroll
            for (int r = 0; r < 4; ++r)
                C[(size_t)(row + r) * N + col] = accP[i][j][r] + accQ[i][j][r] * LO_INV + bv;
        }
    }
}

// ---------------- single-precision f16 MFMA GEMM (decoder): C = A @ W + bias ----------------
// Decoder error is not amplified by the recurrence -> single f16 product suffices.
__global__ __launch_bounds__(256, 2) void mfma_gemm_dec(
    const ushort_t* __restrict__ A, const ushort_t* __restrict__ Wt,
    const float* __restrict__ bias, float* __restrict__ C,
    int M, int N, int K)
{
    const int NB = N >> 7;
    const int mb = blockIdx.x / NB;
    const int nb = blockIdx.x % NB;

    __shared__ __align__(16) ushort_t As[128 * 32];
    __shared__ __align__(16) ushort_t Bs[128 * 32];

    const int tid  = threadIdx.x;
    const int lane = tid & 63;
    const int wave = tid >> 6;
    const int quad = lane >> 4;
    const int l16  = lane & 15;
    const int wm   = wave >> 1;
    const int wn   = wave & 1;

    const int row0 = mb * 128;
    const int col0 = nb * 128;

    f32x4 acc[4][4] = {};

    for (int k0 = 0; k0 < K; k0 += 32) {
#pragma unroll
        for (int i = 0; i < 2; ++i) {
            const int c  = tid + i * 256;
            const int r  = c >> 2;
            const int kc = c & 3;
            gload_lds16(A  + (size_t)(row0 + r) * K + k0 + kc * 8, &As[c * 8]);
            gload_lds16(Wt + (size_t)(col0 + r) * K + k0 + kc * 8, &Bs[c * 8]);
        }
        __syncthreads();

        f16x8 af[4], bf[4];
#pragma unroll
        for (int i = 0; i < 4; ++i)
            af[i] = *(const f16x8*)&As[(wm * 64 + i * 16 + l16) * 32 + quad * 8];
#pragma unroll
        for (int j = 0; j < 4; ++j)
            bf[j] = *(const f16x8*)&Bs[(wn * 64 + j * 16 + l16) * 32 + quad * 8];

#pragma unroll
        for (int i = 0; i < 4; ++i)
#pragma unroll
            for (int j = 0; j < 4; ++j)
                acc[i][j] = __builtin_amdgcn_mfma_f32_16x16x32_f16(af[i], bf[j], acc[i][j], 0, 0, 0);
        __syncthreads();
    }

#pragma unroll
    for (int i = 0; i < 4; ++i) {
        const int row = row0 + wm * 64 + i * 16 + quad * 4;
#pragma unroll
        for (int j = 0; j < 4; ++j) {
            const int col = col0 + wn * 64 + j * 16 + l16;
            const float bv = bias[col];
#pragma unroll
            for (int r = 0; r < 4; ++r)
                C[(size_t)(row + r) * N + col] = acc[i][j][r] + bv;
        }
    }
}

// ---------------- BRC scan: 1 elem/thread, 8-deep prefetch, fast transcendentals ----------------
// fp32 gates in, y out as f16 hi (+ optional lo plane), fp32 recurrence.
// Depth 8: at 1 wave/SIMD the VALU consumption (~70 cyc/iter) must cover ~900-cyc
// HBM latency; 8-deep x 3 streams = 24 outstanding loads/lane ≈ 24 KB in flight/CU.
template <bool WRITE_LO>
__global__ __launch_bounds__(256) void brc_scan_v3(
    const float* __restrict__ xa, const float* __restrict__ xc,
    const float* __restrict__ xh, const float* __restrict__ wa,
    const float* __restrict__ wc, const float* __restrict__ h_in,
    ushort_t* __restrict__ yhi, ushort_t* __restrict__ ylo,
    float* __restrict__ h_out, int T_c)
{
    const int idx = blockIdx.x * 256 + threadIdx.x;   // 0..BH-1
    const int j = idx & (H_DIM - 1);
    float h = h_in[idx];
    const float waj = wa[j], wcj = wc[j];

    float pa[8], pc[8], ph[8];
#pragma unroll
    for (int d = 0; d < 8; ++d) {
        const int dd = (d < T_c) ? d : 0;
        const size_t b = (size_t)dd * BH + idx;
        pa[d] = xa[b]; pc[d] = xc[b]; ph[d] = xh[b];
    }

#pragma unroll 8
    for (int t = 0; t < T_c; ++t) {
        const int s = t & 7;
        const float ca = pa[s], cc = pc[s], ch = ph[s];
        const int tn = t + 8;
        if (tn < T_c) {
            const size_t b = (size_t)tn * BH + idx;
            pa[s] = xa[b]; pc[s] = xc[b]; ph[s] = xh[b];
        }
        const float a = 1.f + ftanh(ca + waj * h);
        const float c = fsig(cc + wcj * h);
        h = c * h + (1.f - c) * ftanh(ch + a * h);

        ushort_t hh, hl;
        split_f16(h, hh, hl);
        const size_t ob = (size_t)t * BH + idx;
        yhi[ob] = hh;
        if (WRITE_LO) ylo[ob] = hl;
    }
    h_out[idx] = h;
}

extern "C" void kernel_launch(void* const* d_in, const int* in_sizes, int n_in,
                              void* d_out, int out_size, void* d_ws, size_t ws_size,
                              hipStream_t stream) {
    const float* x    = (const float*)d_in[0];   // [S,B,IN]
    const float* h0   = (const float*)d_in[1];   // [L,B,H]
    const float* Ua0  = (const float*)d_in[2];
    const float* Uc0  = (const float*)d_in[3];
    const float* Uh0  = (const float*)d_in[4];
    const float* wa0  = (const float*)d_in[5];
    const float* wc0  = (const float*)d_in[6];
    const float* ba0  = (const float*)d_in[7];
    const float* bc0  = (const float*)d_in[8];
    const float* bh0  = (const float*)d_in[9];
    const float* Ua1  = (const float*)d_in[10];
    const float* Uc1  = (const float*)d_in[11];
    const float* Uh1  = (const float*)d_in[12];
    const float* wa1  = (const float*)d_in[13];
    const float* wc1  = (const float*)d_in[14];
    const float* ba1  = (const float*)d_in[15];
    const float* bc1  = (const float*)d_in[16];
    const float* bh1  = (const float*)d_in[17];
    const float* Wdec = (const float*)d_in[18];
    const float* bdec = (const float*)d_in[19];

    float* outF = (float*)d_out;
    float* out_seq  = outF;                                   // [S,B,OUT]
    float* h_last0  = outF + (size_t)S_DIM * B_DIM * OUT_DIM; // [B,H]
    float* h_last1  = h_last0 + BH;                           // [B,H]

    // ---- workspace carve-up ----
    char* wsb = (char*)d_ws;
    size_t off = 0;
    auto alloc = [&](size_t bytes) -> void* {
        void* p = wsb + off;
        off += (bytes + 255) & ~(size_t)255;
        return p;
    };
    const size_t szL0 = (size_t)IN_DIM * H_DIM;
    const size_t szL1 = (size_t)H_DIM * H_DIM;
    const size_t szD  = (size_t)H_DIM * OUT_DIM;
    ushort_t *Wa0h = (ushort_t*)alloc(szL0 * 2), *Wa0l = (ushort_t*)alloc(szL0 * 2);
    ushort_t *Wc0h = (ushort_t*)alloc(szL0 * 2), *Wc0l = (ushort_t*)alloc(szL0 * 2);
    ushort_t *Wh0h = (ushort_t*)alloc(szL0 * 2), *Wh0l = (ushort_t*)alloc(szL0 * 2);
    ushort_t *Wa1h = (ushort_t*)alloc(szL1 * 2), *Wa1l = (ushort_t*)alloc(szL1 * 2);
    ushort_t *Wc1h = (ushort_t*)alloc(szL1 * 2), *Wc1l = (ushort_t*)alloc(szL1 * 2);
    ushort_t *Wh1h = (ushort_t*)alloc(szL1 * 2), *Wh1l = (ushort_t*)alloc(szL1 * 2);
    ushort_t *Wdh  = (ushort_t*)alloc(szD * 2),  *Wdl  = (ushort_t*)alloc(szD * 2);

    // Per-chunk bytes: x hi/lo + 3 fp32 gate planes + y0 hi/lo + y1 hi (no y1 lo)
    const size_t perT = (size_t)2 * B_DIM * IN_DIM * 2 + (size_t)3 * BH * 4 + (size_t)3 * BH * 2;
    int T_c = 512;
    while (T_c > 1 && off + (size_t)T_c * perT + 4096 > ws_size) T_c >>= 1;
    const size_t chunk_elems = (size_t)T_c * BH;
    const size_t xchunk_elems = (size_t)T_c * B_DIM * IN_DIM;

    ushort_t* xhib = (ushort_t*)alloc(xchunk_elems * 2);
    ushort_t* xlob = (ushort_t*)alloc(xchunk_elems * 2);
    float* g_a = (float*)alloc(chunk_elems * 4);
    float* g_c = (float*)alloc(chunk_elems * 4);
    float* g_h = (float*)alloc(chunk_elems * 4);
    ushort_t* y0h = (ushort_t*)alloc(chunk_elems * 2);
    ushort_t* y0l = (ushort_t*)alloc(chunk_elems * 2);
    ushort_t* y1h = (ushort_t*)alloc(chunk_elems * 2);

    const int n_chunks = S_DIM / T_c;
    const int Mc = T_c * B_DIM;

    // ---- one-time per call: weight transpose+split ----
    transpose_split_f16<<<dim3(H_DIM / 32, IN_DIM / 32), 256, 0, stream>>>(Ua0, Wa0h, Wa0l, IN_DIM, H_DIM);
    transpose_split_f16<<<dim3(H_DIM / 32, IN_DIM / 32), 256, 0, stream>>>(Uc0, Wc0h, Wc0l, IN_DIM, H_DIM);
    transpose_split_f16<<<dim3(H_DIM / 32, IN_DIM / 32), 256, 0, stream>>>(Uh0, Wh0h, Wh0l, IN_DIM, H_DIM);
    transpose_split_f16<<<dim3(H_DIM / 32, H_DIM / 32), 256, 0, stream>>>(Ua1, Wa1h, Wa1l, H_DIM, H_DIM);
    transpose_split_f16<<<dim3(H_DIM / 32, H_DIM / 32), 256, 0, stream>>>(Uc1, Wc1h, Wc1l, H_DIM, H_DIM);
    transpose_split_f16<<<dim3(H_DIM / 32, H_DIM / 32), 256, 0, stream>>>(Uh1, Wh1h, Wh1l, H_DIM, H_DIM);
    transpose_split_f16<<<dim3(OUT_DIM / 32, H_DIM / 32), 256, 0, stream>>>(Wdec, Wdh, Wdl, H_DIM, OUT_DIM);

    dim3 blk(256);
    const int grid_g = (H_DIM / 128) * (Mc / 128) * 3;   // 1D swizzled
    const int grid_d = (OUT_DIM / 128) * (Mc / 128);
    dim3 grid_scan(BH / 256);

    for (int ci = 0; ci < n_chunks; ++ci) {
        const float* x_chunk = x + (size_t)ci * Mc * IN_DIM;
        float* out_chunk = out_seq + (size_t)ci * Mc * OUT_DIM;

        // split x chunk -> hi/lo f16 planes
        convert_split_f16<<<dim3((int)(xchunk_elems / 4 / 256)), blk, 0, stream>>>(
            x_chunk, xhib, xlob, (int)xchunk_elems);

        // layer 0 gates: x @ U{a,c,h}0 + b -> fp32 gate buffers
        mfma_gemm3_split<<<dim3(grid_g), blk, 0, stream>>>(
            xhib, xlob, Wa0h, Wa0l, Wc0h, Wc0l, Wh0h, Wh0l,
            ba0, bc0, bh0, g_a, g_c, g_h, Mc, H_DIM, IN_DIM);
        brc_scan_v3<true><<<grid_scan, blk, 0, stream>>>(
            g_a, g_c, g_h, wa0, wc0, (ci == 0) ? h0 : h_last0, y0h, y0l, h_last0, T_c);

        // layer 1 gates: y0 @ U{a,c,h}1 + b
        mfma_gemm3_split<<<dim3(grid_g), blk, 0, stream>>>(
            y0h, y0l, Wa1h, Wa1l, Wc1h, Wc1l, Wh1h, Wh1l,
            ba1, bc1, bh1, g_a, g_c, g_h, Mc, H_DIM, H_DIM);
        brc_scan_v3<false><<<grid_scan, blk, 0, stream>>>(
            g_a, g_c, g_h, wa1, wc1, (ci == 0) ? (h0 + BH) : h_last1, y1h, nullptr, h_last1, T_c);

        // decoder: y1(hi) @ Wdec + bdec -> fp32 out
        mfma_gemm_dec<<<dim3(grid_d), blk, 0, stream>>>(
            y1h, Wdh, bdec, out_chunk, Mc, OUT_DIM, H_DIM);
    }
}